// Round 13
// baseline (152.515 us; speedup 1.0000x reference)
//
#include <hip/hip_runtime.h>
#include <math.h>

#define NN 50000
#define EE 800000
#define INDIM 256
#define DD 32
#define HH 8
#define CC 256   // H*D
#define NEG 0.01f
#define NREP 8        // counter replicas == XCD count (rep-major => XCD-local lines)
#define NSCAN 49      // ceil(NN/1024)
#define PREP_GRID 1024
#define PREP_STRIDE (PREP_GRID * 256)

typedef __attribute__((ext_vector_type(8))) short bf16x8;
typedef __attribute__((ext_vector_type(4))) float f32x4;

__device__ __forceinline__ unsigned short f32_to_bf16_rne(float f) {
  unsigned u = __float_as_uint(f);
  u += 0x7fffu + ((u >> 16) & 1u);
  return (unsigned short)(u >> 16);
}

// ---------- prep: detect + convert(->ushort) + XCD-local histogram + W->bf16 ----------
__global__ __launch_bounds__(256) void k_prep(const unsigned* __restrict__ sraw,
                                              const unsigned* __restrict__ draw,
                                              int* __restrict__ counts8,
                                              unsigned short* __restrict__ s16,
                                              unsigned short* __restrict__ d16,
                                              unsigned short* __restrict__ slot16,
                                              const float* __restrict__ W,
                                              unsigned short* __restrict__ WbT) {
  __shared__ int sflag;
  if (threadIdx.x == 0) sflag = 0;
  __syncthreads();
  const int gt = blockIdx.x * 256 + threadIdx.x;
  unsigned v = 0;
#pragma unroll
  for (int i = 0; i < 4; ++i) {
    int e = (gt * 4 + i) % (EE / 2);
    v |= sraw[2 * e + 1] | draw[2 * e + 1];
  }
  if (v) atomicOr(&sflag, 1);
  __syncthreads();
  const int is32 = sflag;   // 1 => int32 indices

  const int rep = blockIdx.x & (NREP - 1);
  int* __restrict__ mycounts = counts8 + rep * NN;

  for (int e = gt; e < EE; e += PREP_STRIDE) {
    int sv, dv;
    if (is32) {
      sv = ((const int*)sraw)[e];
      dv = ((const int*)draw)[e];
    } else {
      sv = (int)((const long long*)sraw)[e];
      dv = (int)((const long long*)draw)[e];
    }
    s16[e] = (unsigned short)sv;
    d16[e] = (unsigned short)dv;
    slot16[e] = (unsigned short)atomicAdd(&mycounts[dv], 1);
  }

  // W -> WbT[n][k] = W[h][k][d], n=h*32+d (B^T layout)
  if (gt < INDIM * CC) {
    int n = gt >> 8, k = gt & 255;
    int hh = n >> 5, d = n & 31;
    WbT[gt] = f32_to_bf16_rne(W[(size_t)hh * 8192 + k * 32 + d]);
  }
}

// ---------- z = h @ W via bf16 MFMA; epilogue: el/er + per-(node,head) int8 quantized z ----------
// elsc[node*8+head] = float2{ el , scale }  (node's 8 heads = one 64B line)
__global__ __launch_bounds__(512) void k_gemm(const float* __restrict__ h,
                                              const unsigned short* __restrict__ WbT,
                                              const float* __restrict__ attn_w,
                                              signed char* __restrict__ z8,
                                              float2* __restrict__ elsc,
                                              float* __restrict__ er) {
  __shared__ short sA[64 * 256];   // 32 KB, [64 nodes][256 k], chunk-swizzled
  const int t = threadIdx.x;
  const int l = t & 63;
  const int w = t >> 6;            // wave index == head
  const int row0 = blockIdx.x * 64;

#pragma unroll
  for (int i = 0; i < 4; ++i) {
    int q = i * 512 + t;
    int row = q >> 5, c = q & 31;
    int grow = row0 + row; if (grow >= NN) grow = NN - 1;
    const float* src = &h[(size_t)grow * 256 + c * 8];
    float4 f0 = *reinterpret_cast<const float4*>(src);
    float4 f1 = *reinterpret_cast<const float4*>(src + 4);
    bf16x8 vv;
    vv[0] = (short)f32_to_bf16_rne(f0.x); vv[1] = (short)f32_to_bf16_rne(f0.y);
    vv[2] = (short)f32_to_bf16_rne(f0.z); vv[3] = (short)f32_to_bf16_rne(f0.w);
    vv[4] = (short)f32_to_bf16_rne(f1.x); vv[5] = (short)f32_to_bf16_rne(f1.y);
    vv[6] = (short)f32_to_bf16_rne(f1.z); vv[7] = (short)f32_to_bf16_rne(f1.w);
    int sc = c ^ (row & 7);
    *reinterpret_cast<bf16x8*>(&sA[row * 256 + sc * 8]) = vv;
  }

  bf16x8 bf[2][8];
  {
    const int n = w * 32 + (l & 15);
    const int kb = (l >> 4) * 8;
#pragma unroll
    for (int c = 0; c < 2; ++c)
#pragma unroll
      for (int kk = 0; kk < 8; ++kk)
        bf[c][kk] = *reinterpret_cast<const bf16x8*>(
            &WbT[(size_t)(n + c * 16) * 256 + kk * 32 + kb]);
  }

  f32x4 acc[4][2];
#pragma unroll
  for (int m = 0; m < 4; ++m)
#pragma unroll
    for (int c = 0; c < 2; ++c) acc[m][c] = (f32x4){0.f, 0.f, 0.f, 0.f};

  __syncthreads();

#pragma unroll
  for (int kk = 0; kk < 8; ++kk) {
    bf16x8 af[4];
#pragma unroll
    for (int m = 0; m < 4; ++m) {
      int row = m * 16 + (l & 15);
      int chunk = kk * 4 + (l >> 4);
      int sc = chunk ^ (row & 7);
      af[m] = *reinterpret_cast<const bf16x8*>(&sA[row * 256 + sc * 8]);
    }
#pragma unroll
    for (int m = 0; m < 4; ++m)
#pragma unroll
      for (int c = 0; c < 2; ++c)
        acc[m][c] = __builtin_amdgcn_mfma_f32_16x16x32_bf16(bf[c][kk], af[m], acc[m][c], 0, 0, 0);
  }

  float alc[2][4], arc[2][4];
#pragma unroll
  for (int c = 0; c < 2; ++c)
#pragma unroll
    for (int r = 0; r < 4; ++r) {
      int d = c * 16 + ((l >> 4) << 2) + r;
      alc[c][r] = attn_w[w * 64 + d];
      arc[c][r] = attn_w[w * 64 + 32 + d];
    }

#pragma unroll
  for (int m = 0; m < 4; ++m) {
    int node = row0 + m * 16 + (l & 15);
    float pl = 0.f, pr = 0.f, pm = 0.f;
#pragma unroll
    for (int c = 0; c < 2; ++c)
#pragma unroll
      for (int r = 0; r < 4; ++r) {
        float a = acc[m][c][r];
        pl += a * alc[c][r];
        pr += a * arc[c][r];
        pm = fmaxf(pm, fabsf(a));
      }
    pl += __shfl_xor(pl, 16); pl += __shfl_xor(pl, 32);
    pr += __shfl_xor(pr, 16); pr += __shfl_xor(pr, 32);
    pm = fmaxf(pm, __shfl_xor(pm, 16)); pm = fmaxf(pm, __shfl_xor(pm, 32));
    const float rcp = (pm > 0.f) ? (127.f / pm) : 0.f;

    if (node < NN) {
#pragma unroll
      for (int c = 0; c < 2; ++c) {
        unsigned wq = 0;
#pragma unroll
        for (int r = 0; r < 4; ++r) {
          int q = __float2int_rn(acc[m][c][r] * rcp);
          wq |= ((unsigned)(q & 255)) << (8 * r);
        }
        *reinterpret_cast<unsigned*>(
            &z8[(size_t)node * CC + w * 32 + c * 16 + ((l >> 4) << 2)]) = wq;
      }
      if ((l >> 4) == 0) {
        float2 e2; e2.x = pl; e2.y = pm * (1.f / 127.f);
        elsc[(size_t)node * 8 + w] = e2;
        er[(size_t)node * HH + w] = pr;
      }
    }
  }
}

// ---------- scan: fold 8 rep-counts -> degree scan + per-(node,rep) offsets ----------
__global__ __launch_bounds__(1024) void k_scan(const int* __restrict__ counts8,
                                               int* __restrict__ row_start,
                                               int* __restrict__ partial,
                                               unsigned char* __restrict__ offs8) {
  __shared__ int s[1024];
  const int tid = threadIdx.x;
  const int i = blockIdx.x * 1024 + tid;
  int deg = 0;
  if (i < NN) {
    unsigned pack0 = 0, pack1 = 0;
    int run = 0;
#pragma unroll
    for (int r = 0; r < NREP; ++r) {
      int c = counts8[r * NN + i];
      if (r < 4) pack0 |= (unsigned)run << (8 * r);
      else       pack1 |= (unsigned)run << (8 * (r - 4));
      run += c;
    }
    deg = run;
    uint2 pk; pk.x = pack0; pk.y = pack1;
    *reinterpret_cast<uint2*>(&offs8[(size_t)i * 8]) = pk;
  }
  s[tid] = deg;
  __syncthreads();
  for (int off = 1; off < 1024; off <<= 1) {
    int tv = (tid >= off) ? s[tid - off] : 0;
    __syncthreads();
    s[tid] += tv;
    __syncthreads();
  }
  if (i < NN) row_start[i] = s[tid] - deg;         // exclusive within chunk
  if (tid == 1023) partial[blockIdx.x] = s[1023];  // raw chunk total
}

__device__ __forceinline__ void block_base_scan(const int* __restrict__ partial,
                                                int* __restrict__ sbase) {
  if (threadIdx.x < 64) {
    int l = threadIdx.x;
    int x = (l < NSCAN) ? partial[l] : 0;
    int orig = x;
#pragma unroll
    for (int off = 1; off < 64; off <<= 1) {
      int y = __shfl_up(x, off);
      if (l >= off) x += y;
    }
    sbase[l] = x - orig;
  }
  __syncthreads();
}

// ---------- scatter: atomic-free, contiguous per-node CSR ----------
__global__ __launch_bounds__(256) void k_scatter(const unsigned short* __restrict__ s16,
                                                 const unsigned short* __restrict__ d16,
                                                 const unsigned short* __restrict__ slot16,
                                                 const unsigned char* __restrict__ offs8,
                                                 const int* __restrict__ row_start,
                                                 const int* __restrict__ partial,
                                                 unsigned short* __restrict__ csr16) {
  __shared__ int sbase[64];
  block_base_scan(partial, sbase);
  int stride = gridDim.x * blockDim.x;
  for (int e = blockIdx.x * blockDim.x + threadIdx.x; e < EE; e += stride) {
    int dn = (int)d16[e];
    int rep = ((e & (PREP_STRIDE - 1)) >> 8) & (NREP - 1);
    int pos = row_start[dn] + sbase[dn >> 10] + (int)offs8[dn * 8 + rep] + (int)slot16[e];
    csr16[pos] = s16[e];
  }
}

// ---------- per-node softmax-aggregate: dual-node per wave (2x gather MLP) ----------
#define AGG_WAVES 8192
__global__ __launch_bounds__(256) void k_agg(const unsigned* __restrict__ z8u,
                                             const float2* __restrict__ elsc,
                                             const float* __restrict__ er,
                                             const int* __restrict__ row_start,
                                             const int* __restrict__ partial,
                                             const unsigned short* __restrict__ csr16,
                                             float* __restrict__ out) {
  __shared__ int sbase[64];
  block_base_scan(partial, sbase);

  const int gw = blockIdx.x * 4 + (threadIdx.x >> 6);
  const int l = threadIdx.x & 63;
  const int head = l >> 3;

  for (int n0 = gw * 2; n0 < NN; n0 += AGG_WAVES * 2) {
    const int n1 = n0 + 1;   // NN even, n0 even -> n1 < NN
    const int b0 = row_start[n0] + sbase[n0 >> 10];
    const int e0 = row_start[n1] + sbase[n1 >> 10];
    const int b1 = e0;
    const int e1 = (n1 == NN - 1) ? EE : (row_start[n1 + 1] + sbase[(n1 + 1) >> 10]);
    const float ern0 = er[(size_t)n0 * HH + head];
    const float ern1 = er[(size_t)n1 * HH + head];

    float den0 = 0.f, den1 = 0.f;
    float a00 = 0.f, a01 = 0.f, a02 = 0.f, a03 = 0.f;
    float a10 = 0.f, a11 = 0.f, a12 = 0.f, a13 = 0.f;

    const int cd = min(e0 - b0, e1 - b1);
#pragma unroll 2
    for (int i = 0; i < cd; ++i) {
      int sA_ = (int)csr16[b0 + i];
      int sB_ = (int)csr16[b1 + i];
      float2 eA = elsc[(size_t)sA_ * 8 + head];
      float2 eB = elsc[(size_t)sB_ * 8 + head];
      unsigned qA = z8u[(size_t)sA_ * 64 + l];
      unsigned qB = z8u[(size_t)sB_ * 64 + l];
      float vA = eA.x + ern0; vA = (vA > 0.f) ? vA : vA * NEG;
      float vB = eB.x + ern1; vB = (vB > 0.f) ? vB : vB * NEG;
      float wA = __expf(vA), wB = __expf(vB);
      den0 += wA; den1 += wB;
      float wsA = wA * eA.y, wsB = wB * eB.y;
      a00 += wsA * (float)(int)(signed char)(qA & 255);
      a01 += wsA * (float)(int)(signed char)((qA >> 8) & 255);
      a02 += wsA * (float)(int)(signed char)((qA >> 16) & 255);
      a03 += wsA * (float)(int)(signed char)(qA >> 24);
      a10 += wsB * (float)(int)(signed char)(qB & 255);
      a11 += wsB * (float)(int)(signed char)((qB >> 8) & 255);
      a12 += wsB * (float)(int)(signed char)((qB >> 16) & 255);
      a13 += wsB * (float)(int)(signed char)(qB >> 24);
    }
    for (int p = b0 + cd; p < e0; ++p) {
      int s = (int)csr16[p];
      float2 eA = elsc[(size_t)s * 8 + head];
      unsigned qA = z8u[(size_t)s * 64 + l];
      float v = eA.x + ern0; v = (v > 0.f) ? v : v * NEG;
      float w = __expf(v);
      den0 += w;
      float ws = w * eA.y;
      a00 += ws * (float)(int)(signed char)(qA & 255);
      a01 += ws * (float)(int)(signed char)((qA >> 8) & 255);
      a02 += ws * (float)(int)(signed char)((qA >> 16) & 255);
      a03 += ws * (float)(int)(signed char)(qA >> 24);
    }
    for (int p = b1 + cd; p < e1; ++p) {
      int s = (int)csr16[p];
      float2 eB = elsc[(size_t)s * 8 + head];
      unsigned qB = z8u[(size_t)s * 64 + l];
      float v = eB.x + ern1; v = (v > 0.f) ? v : v * NEG;
      float w = __expf(v);
      den1 += w;
      float ws = w * eB.y;
      a10 += ws * (float)(int)(signed char)(qB & 255);
      a11 += ws * (float)(int)(signed char)((qB >> 8) & 255);
      a12 += ws * (float)(int)(signed char)((qB >> 16) & 255);
      a13 += ws * (float)(int)(signed char)(qB >> 24);
    }

    const float rd0 = (e0 > b0) ? (1.f / den0) : 0.f;
    const float rd1 = (e1 > b1) ? (1.f / den1) : 0.f;
    float4 o0; o0.x = a00 * rd0; o0.y = a01 * rd0; o0.z = a02 * rd0; o0.w = a03 * rd0;
    float4 o1; o1.x = a10 * rd1; o1.y = a11 * rd1; o1.z = a12 * rd1; o1.w = a13 * rd1;
    *reinterpret_cast<float4*>(&out[(size_t)n0 * CC + 4 * l]) = o0;
    *reinterpret_cast<float4*>(&out[(size_t)n1 * CC + 4 * l]) = o1;
  }
}

extern "C" void kernel_launch(void* const* d_in, const int* in_sizes, int n_in,
                              void* d_out, int out_size, void* d_ws, size_t ws_size,
                              hipStream_t stream) {
  const float* h      = (const float*)d_in[0];
  const float* W      = (const float*)d_in[1];
  const float* attn_w = (const float*)d_in[2];
  const void*  src_raw = d_in[3];
  const void*  dst_raw = d_in[4];
  float* out = (float*)d_out;

  char* ws = (char*)d_ws;
  size_t off = 0;
  signed char* z8     = (signed char*)(ws + off); off += (size_t)NN * CC;            // 12.8 MB
  unsigned short* WbT = (unsigned short*)(ws + off); off += (size_t)INDIM * CC * 2;  // 128 KB
  float2* elsc = (float2*)(ws + off); off += (size_t)NN * 8 * 8;  // 3.2 MB ({el,scale} x 8 heads)
  float* er   = (float*)(ws + off); off += (size_t)NN * HH * 4;   // 1.6 MB
  int* counts8 = (int*)(ws + off); off += (size_t)NREP * NN * 4;  // 1.6 MB (memset)
  int* row_start = (int*)(ws + off); off += (size_t)NN * 4;
  int* partial   = (int*)(ws + off); off += 256;
  unsigned char* offs8 = (unsigned char*)(ws + off); off += (size_t)NN * 8;   // 400 KB
  unsigned short* s16    = (unsigned short*)(ws + off); off += (size_t)EE * 2; // 1.6 MB
  unsigned short* d16    = (unsigned short*)(ws + off); off += (size_t)EE * 2; // 1.6 MB
  unsigned short* slot16 = (unsigned short*)(ws + off); off += (size_t)EE * 2; // 1.6 MB
  unsigned short* csr16  = (unsigned short*)(ws + off); off += (size_t)EE * 2; // 1.6 MB

  hipMemsetAsync(counts8, 0, (size_t)NREP * NN * 4, stream);

  k_prep<<<PREP_GRID, 256, 0, stream>>>((const unsigned*)src_raw, (const unsigned*)dst_raw,
                                        counts8, s16, d16, slot16, W, WbT);

  k_gemm<<<(NN + 63) / 64, 512, 0, stream>>>(h, WbT, attn_w, z8, elsc, er);

  k_scan<<<NSCAN, 1024, 0, stream>>>(counts8, row_start, partial, offs8);

  k_scatter<<<2048, 256, 0, stream>>>(s16, d16, slot16, offs8, row_start, partial, csr16);

  k_agg<<<AGG_WAVES / 4, 256, 0, stream>>>((const unsigned*)z8, elsc, er,
                                           row_start, partial, csr16, out);
}

// Round 14
// 145.325 us; speedup vs baseline: 1.0495x; 1.0495x over previous
//
#include <hip/hip_runtime.h>
#include <math.h>

#define NN 50000
#define EE 800000
#define INDIM 256
#define DD 32
#define HH 8
#define CC 256   // H*D
#define NEG 0.01f
#define NREP 8        // counter replicas == XCD count (rep-major => XCD-local lines)
#define NSCAN 49      // ceil(NN/1024)
#define PREP_GRID 2048
#define PREP_STRIDE (PREP_GRID * 256)   // power of 2, > EE/2 (rep-recompute in scatter relies on this)

typedef __attribute__((ext_vector_type(8))) short bf16x8;
typedef __attribute__((ext_vector_type(4))) float f32x4;

__device__ __forceinline__ unsigned short f32_to_bf16_rne(float f) {
  unsigned u = __float_as_uint(f);
  u += 0x7fffu + ((u >> 16) & 1u);
  return (unsigned short)(u >> 16);
}

// ---------- prep: detect + convert(->packed u32) + XCD-local histogram + W->bf16 ----------
__global__ __launch_bounds__(256) void k_prep(const unsigned* __restrict__ sraw,
                                              const unsigned* __restrict__ draw,
                                              int* __restrict__ counts8,
                                              unsigned* __restrict__ sd32,
                                              unsigned short* __restrict__ slot16,
                                              const float* __restrict__ W,
                                              unsigned short* __restrict__ WbT) {
  __shared__ int sflag;
  if (threadIdx.x == 0) sflag = 0;
  __syncthreads();
  const int gt = blockIdx.x * 256 + threadIdx.x;
  unsigned v = 0;
#pragma unroll
  for (int i = 0; i < 2; ++i) {
    int e = (gt * 2 + i) % (EE / 2);
    v |= sraw[2 * e + 1] | draw[2 * e + 1];
  }
  if (v) atomicOr(&sflag, 1);
  __syncthreads();
  const int is32 = sflag;   // 1 => int32 indices

  const int rep = blockIdx.x & (NREP - 1);
  int* __restrict__ mycounts = counts8 + rep * NN;

  for (int e = gt; e < EE; e += PREP_STRIDE) {
    int sv, dv;
    if (is32) {
      sv = ((const int*)sraw)[e];
      dv = ((const int*)draw)[e];
    } else {
      sv = (int)((const long long*)sraw)[e];
      dv = (int)((const long long*)draw)[e];
    }
    sd32[e] = ((unsigned)dv << 16) | (unsigned)sv;
    slot16[e] = (unsigned short)atomicAdd(&mycounts[dv], 1);
  }

  // W -> WbT[n][k] = W[h][k][d], n=h*32+d (B^T layout)
  if (gt < INDIM * CC) {
    int n = gt >> 8, k = gt & 255;
    int hh = n >> 5, d = n & 31;
    WbT[gt] = f32_to_bf16_rne(W[(size_t)hh * 8192 + k * 32 + d]);
  }
}

// ---------- z = h @ W via bf16 MFMA; epilogue: el/er + per-(node,head) int8 quantized z ----------
// elsc[node*8+head] = float2{ el , scale }  (node's 8 heads = one 64B line)
__global__ __launch_bounds__(512) void k_gemm(const float* __restrict__ h,
                                              const unsigned short* __restrict__ WbT,
                                              const float* __restrict__ attn_w,
                                              signed char* __restrict__ z8,
                                              float2* __restrict__ elsc,
                                              float* __restrict__ er) {
  __shared__ short sA[64 * 256];   // 32 KB, [64 nodes][256 k], chunk-swizzled
  const int t = threadIdx.x;
  const int l = t & 63;
  const int w = t >> 6;            // wave index == head
  const int row0 = blockIdx.x * 64;

#pragma unroll
  for (int i = 0; i < 4; ++i) {
    int q = i * 512 + t;
    int row = q >> 5, c = q & 31;
    int grow = row0 + row; if (grow >= NN) grow = NN - 1;
    const float* src = &h[(size_t)grow * 256 + c * 8];
    float4 f0 = *reinterpret_cast<const float4*>(src);
    float4 f1 = *reinterpret_cast<const float4*>(src + 4);
    bf16x8 vv;
    vv[0] = (short)f32_to_bf16_rne(f0.x); vv[1] = (short)f32_to_bf16_rne(f0.y);
    vv[2] = (short)f32_to_bf16_rne(f0.z); vv[3] = (short)f32_to_bf16_rne(f0.w);
    vv[4] = (short)f32_to_bf16_rne(f1.x); vv[5] = (short)f32_to_bf16_rne(f1.y);
    vv[6] = (short)f32_to_bf16_rne(f1.z); vv[7] = (short)f32_to_bf16_rne(f1.w);
    int sc = c ^ (row & 7);
    *reinterpret_cast<bf16x8*>(&sA[row * 256 + sc * 8]) = vv;
  }

  bf16x8 bf[2][8];
  {
    const int n = w * 32 + (l & 15);
    const int kb = (l >> 4) * 8;
#pragma unroll
    for (int c = 0; c < 2; ++c)
#pragma unroll
      for (int kk = 0; kk < 8; ++kk)
        bf[c][kk] = *reinterpret_cast<const bf16x8*>(
            &WbT[(size_t)(n + c * 16) * 256 + kk * 32 + kb]);
  }

  f32x4 acc[4][2];
#pragma unroll
  for (int m = 0; m < 4; ++m)
#pragma unroll
    for (int c = 0; c < 2; ++c) acc[m][c] = (f32x4){0.f, 0.f, 0.f, 0.f};

  __syncthreads();

#pragma unroll
  for (int kk = 0; kk < 8; ++kk) {
    bf16x8 af[4];
#pragma unroll
    for (int m = 0; m < 4; ++m) {
      int row = m * 16 + (l & 15);
      int chunk = kk * 4 + (l >> 4);
      int sc = chunk ^ (row & 7);
      af[m] = *reinterpret_cast<const bf16x8*>(&sA[row * 256 + sc * 8]);
    }
#pragma unroll
    for (int m = 0; m < 4; ++m)
#pragma unroll
      for (int c = 0; c < 2; ++c)
        acc[m][c] = __builtin_amdgcn_mfma_f32_16x16x32_bf16(bf[c][kk], af[m], acc[m][c], 0, 0, 0);
  }

  float alc[2][4], arc[2][4];
#pragma unroll
  for (int c = 0; c < 2; ++c)
#pragma unroll
    for (int r = 0; r < 4; ++r) {
      int d = c * 16 + ((l >> 4) << 2) + r;
      alc[c][r] = attn_w[w * 64 + d];
      arc[c][r] = attn_w[w * 64 + 32 + d];
    }

#pragma unroll
  for (int m = 0; m < 4; ++m) {
    int node = row0 + m * 16 + (l & 15);
    float pl = 0.f, pr = 0.f, pm = 0.f;
#pragma unroll
    for (int c = 0; c < 2; ++c)
#pragma unroll
      for (int r = 0; r < 4; ++r) {
        float a = acc[m][c][r];
        pl += a * alc[c][r];
        pr += a * arc[c][r];
        pm = fmaxf(pm, fabsf(a));
      }
    pl += __shfl_xor(pl, 16); pl += __shfl_xor(pl, 32);
    pr += __shfl_xor(pr, 16); pr += __shfl_xor(pr, 32);
    pm = fmaxf(pm, __shfl_xor(pm, 16)); pm = fmaxf(pm, __shfl_xor(pm, 32));
    const float rcp = (pm > 0.f) ? (127.f / pm) : 0.f;

    if (node < NN) {
#pragma unroll
      for (int c = 0; c < 2; ++c) {
        unsigned wq = 0;
#pragma unroll
        for (int r = 0; r < 4; ++r) {
          int q = __float2int_rn(acc[m][c][r] * rcp);
          wq |= ((unsigned)(q & 255)) << (8 * r);
        }
        *reinterpret_cast<unsigned*>(
            &z8[(size_t)node * CC + w * 32 + c * 16 + ((l >> 4) << 2)]) = wq;
      }
      if ((l >> 4) == 0) {
        float2 e2; e2.x = pl; e2.y = pm * (1.f / 127.f);
        elsc[(size_t)node * 8 + w] = e2;
        er[(size_t)node * HH + w] = pr;
      }
    }
  }
}

// ---------- scan: fold 8 rep-counts -> degree scan + per-(node,rep) offsets ----------
__global__ __launch_bounds__(1024) void k_scan(const int* __restrict__ counts8,
                                               int* __restrict__ row_start,
                                               int* __restrict__ partial,
                                               unsigned char* __restrict__ offs8) {
  __shared__ int s[1024];
  const int tid = threadIdx.x;
  const int i = blockIdx.x * 1024 + tid;
  int deg = 0;
  if (i < NN) {
    unsigned pack0 = 0, pack1 = 0;
    int run = 0;
#pragma unroll
    for (int r = 0; r < NREP; ++r) {
      int c = counts8[r * NN + i];
      if (r < 4) pack0 |= (unsigned)run << (8 * r);
      else       pack1 |= (unsigned)run << (8 * (r - 4));
      run += c;
    }
    deg = run;
    uint2 pk; pk.x = pack0; pk.y = pack1;
    *reinterpret_cast<uint2*>(&offs8[(size_t)i * 8]) = pk;
  }
  s[tid] = deg;
  __syncthreads();
  for (int off = 1; off < 1024; off <<= 1) {
    int tv = (tid >= off) ? s[tid - off] : 0;
    __syncthreads();
    s[tid] += tv;
    __syncthreads();
  }
  if (i < NN) row_start[i] = s[tid] - deg;         // exclusive within chunk
  if (tid == 1023) partial[blockIdx.x] = s[1023];  // raw chunk total
}

__device__ __forceinline__ void block_base_scan(const int* __restrict__ partial,
                                                int* __restrict__ sbase) {
  if (threadIdx.x < 64) {
    int l = threadIdx.x;
    int x = (l < NSCAN) ? partial[l] : 0;
    int orig = x;
#pragma unroll
    for (int off = 1; off < 64; off <<= 1) {
      int y = __shfl_up(x, off);
      if (l >= off) x += y;
    }
    sbase[l] = x - orig;
  }
  __syncthreads();
}

// ---------- scatter: atomic-free, contiguous per-node CSR ----------
// rep recomputed from e (prep's static e->block map): rep = ((e % PREP_STRIDE) >> 8) & 7
__global__ __launch_bounds__(256) void k_scatter(const unsigned* __restrict__ sd32,
                                                 const unsigned short* __restrict__ slot16,
                                                 const unsigned char* __restrict__ offs8,
                                                 const int* __restrict__ row_start,
                                                 const int* __restrict__ partial,
                                                 unsigned short* __restrict__ csr16) {
  __shared__ int sbase[64];
  block_base_scan(partial, sbase);
  int stride = gridDim.x * blockDim.x;
  for (int e = blockIdx.x * blockDim.x + threadIdx.x; e < EE; e += stride) {
    unsigned sd = sd32[e];
    int dn = (int)(sd >> 16);
    int rep = ((e & (PREP_STRIDE - 1)) >> 8) & (NREP - 1);
    int pos = row_start[dn] + sbase[dn >> 10] + (int)offs8[dn * 8 + rep] + (int)slot16[e];
    csr16[pos] = (unsigned short)(sd & 0xFFFFu);
  }
}

// ---------- per-node softmax-aggregate (R12 known-best body; float2 elsc) ----------
#define AGG_WAVES 8192
__global__ __launch_bounds__(256) void k_agg(const unsigned* __restrict__ z8u,
                                             const float2* __restrict__ elsc,
                                             const float* __restrict__ er,
                                             const int* __restrict__ row_start,
                                             const int* __restrict__ partial,
                                             const unsigned short* __restrict__ csr16,
                                             float* __restrict__ out) {
  __shared__ int sbase[64];
  block_base_scan(partial, sbase);

  const int gw = blockIdx.x * 4 + (threadIdx.x >> 6);
  const int l = threadIdx.x & 63;
  const int head = l >> 3;

  for (int n = gw; n < NN; n += AGG_WAVES) {
    const int beg = row_start[n] + sbase[n >> 10];
    const int end = (n == NN - 1) ? EE : (row_start[n + 1] + sbase[(n + 1) >> 10]);
    const float ern = er[(size_t)n * HH + head];

    float den = 0.f;
    float a0 = 0.f, a1 = 0.f, a2 = 0.f, a3 = 0.f;
#pragma unroll 4
    for (int p = beg; p < end; ++p) {
      int s = (int)csr16[p];
      float2 e2 = elsc[(size_t)s * 8 + head];
      float v = e2.x + ern;
      v = (v > 0.f) ? v : v * NEG;
      float wgt = __expf(v);
      unsigned wq = z8u[(size_t)s * 64 + l];
      den += wgt;
      float ws = wgt * e2.y;
      a0 += ws * (float)(int)(signed char)(wq & 255);
      a1 += ws * (float)(int)(signed char)((wq >> 8) & 255);
      a2 += ws * (float)(int)(signed char)((wq >> 16) & 255);
      a3 += ws * (float)(int)(signed char)(wq >> 24);
    }
    const float rd = (end > beg) ? (1.f / den) : 0.f;
    float4 o;
    o.x = a0 * rd; o.y = a1 * rd; o.z = a2 * rd; o.w = a3 * rd;
    *reinterpret_cast<float4*>(&out[(size_t)n * CC + 4 * l]) = o;
  }
}

extern "C" void kernel_launch(void* const* d_in, const int* in_sizes, int n_in,
                              void* d_out, int out_size, void* d_ws, size_t ws_size,
                              hipStream_t stream) {
  const float* h      = (const float*)d_in[0];
  const float* W      = (const float*)d_in[1];
  const float* attn_w = (const float*)d_in[2];
  const void*  src_raw = d_in[3];
  const void*  dst_raw = d_in[4];
  float* out = (float*)d_out;

  char* ws = (char*)d_ws;
  size_t off = 0;
  signed char* z8     = (signed char*)(ws + off); off += (size_t)NN * CC;            // 12.8 MB
  unsigned short* WbT = (unsigned short*)(ws + off); off += (size_t)INDIM * CC * 2;  // 128 KB
  float2* elsc = (float2*)(ws + off); off += (size_t)NN * 8 * 8;  // 3.2 MB ({el,scale} x 8 heads)
  float* er   = (float*)(ws + off); off += (size_t)NN * HH * 4;   // 1.6 MB
  int* counts8 = (int*)(ws + off); off += (size_t)NREP * NN * 4;  // 1.6 MB (memset)
  int* row_start = (int*)(ws + off); off += (size_t)NN * 4;
  int* partial   = (int*)(ws + off); off += 256;
  unsigned char* offs8 = (unsigned char*)(ws + off); off += (size_t)NN * 8;    // 400 KB
  unsigned* sd32         = (unsigned*)(ws + off); off += (size_t)EE * 4;       // 3.2 MB
  unsigned short* slot16 = (unsigned short*)(ws + off); off += (size_t)EE * 2; // 1.6 MB
  unsigned short* csr16  = (unsigned short*)(ws + off); off += (size_t)EE * 2; // 1.6 MB

  hipMemsetAsync(counts8, 0, (size_t)NREP * NN * 4, stream);

  k_prep<<<PREP_GRID, 256, 0, stream>>>((const unsigned*)src_raw, (const unsigned*)dst_raw,
                                        counts8, sd32, slot16, W, WbT);

  k_gemm<<<(NN + 63) / 64, 512, 0, stream>>>(h, WbT, attn_w, z8, elsc, er);

  k_scan<<<NSCAN, 1024, 0, stream>>>(counts8, row_start, partial, offs8);

  k_scatter<<<2048, 256, 0, stream>>>(sd32, slot16, offs8, row_start, partial, csr16);

  k_agg<<<AGG_WAVES / 4, 256, 0, stream>>>((const unsigned*)z8, elsc, er,
                                           row_start, partial, csr16, out);
}

// Round 15
// 144.169 us; speedup vs baseline: 1.0579x; 1.0080x over previous
//
#include <hip/hip_runtime.h>
#include <hip/hip_bf16.h>
#include <math.h>

#define NN 50000
#define EE 800000
#define INDIM 256
#define DD 32
#define HH 8
#define CC 256   // H*D
#define NEG 0.01f
#define NREP 8        // counter replicas == XCD count (rep-major => XCD-local lines)
#define NSCAN 49      // ceil(NN/1024)
#define PREP_GRID 2048
#define PREP_STRIDE (PREP_GRID * 256)   // power of 2 (scatter's rep-recompute relies on this)

typedef __attribute__((ext_vector_type(8))) short bf16x8;
typedef __attribute__((ext_vector_type(4))) float f32x4;

__device__ __forceinline__ unsigned short f32_to_bf16_rne(float f) {
  unsigned u = __float_as_uint(f);
  u += 0x7fffu + ((u >> 16) & 1u);
  return (unsigned short)(u >> 16);
}
__device__ __forceinline__ unsigned pack_bf16x2(float a, float b) {
  __hip_bfloat162 p = __float22bfloat162_rn(make_float2(a, b));  // v_cvt_pk_bf16_f32 (RNE)
  return *reinterpret_cast<unsigned*>(&p);
}

// ---------- prep: detect + convert(->packed u32) + XCD-local histogram + W->bf16 ----------
__global__ __launch_bounds__(256) void k_prep(const unsigned* __restrict__ sraw,
                                              const unsigned* __restrict__ draw,
                                              int* __restrict__ counts8,
                                              unsigned* __restrict__ sd32,
                                              unsigned short* __restrict__ slot16,
                                              const float* __restrict__ W,
                                              unsigned short* __restrict__ WbT) {
  __shared__ int sflag;
  if (threadIdx.x == 0) sflag = 0;
  __syncthreads();
  const int gt = blockIdx.x * 256 + threadIdx.x;
  unsigned v = 0;
#pragma unroll
  for (int i = 0; i < 2; ++i) {
    int e = (gt * 2 + i) % (EE / 2);
    v |= sraw[2 * e + 1] | draw[2 * e + 1];
  }
  if (v) atomicOr(&sflag, 1);
  __syncthreads();
  const int is32 = sflag;   // 1 => int32 indices

  const int rep = blockIdx.x & (NREP - 1);
  int* __restrict__ mycounts = counts8 + rep * NN;

  for (int e = gt; e < EE; e += PREP_STRIDE) {
    int sv, dv;
    if (is32) {
      sv = ((const int*)sraw)[e];
      dv = ((const int*)draw)[e];
    } else {
      sv = (int)((const long long*)sraw)[e];
      dv = (int)((const long long*)draw)[e];
    }
    sd32[e] = ((unsigned)dv << 16) | (unsigned)sv;
    slot16[e] = (unsigned short)atomicAdd(&mycounts[dv], 1);
  }

  // W -> WbT[n][k] = W[h][k][d], n=h*32+d (B^T layout)
  if (gt < INDIM * CC) {
    int n = gt >> 8, k = gt & 255;
    int hh = n >> 5, d = n & 31;
    WbT[gt] = f32_to_bf16_rne(W[(size_t)hh * 8192 + k * 32 + d]);
  }
}

// ---------- z = h @ W via bf16 MFMA; epilogue: el/er + per-(node,head) int8 quantized z ----------
// elsc[node*16 + head] = el ; elsc[node*16 + 8 + head] = scale  (node's 16 floats = one 64B line)
__global__ __launch_bounds__(512) void k_gemm(const float* __restrict__ h,
                                              const unsigned short* __restrict__ WbT,
                                              const float* __restrict__ attn_w,
                                              signed char* __restrict__ z8,
                                              float* __restrict__ elsc,
                                              float* __restrict__ er) {
  __shared__ short sA[64 * 256];   // 32 KB, [64 nodes][256 k], chunk-swizzled
  const int t = threadIdx.x;
  const int l = t & 63;
  const int w = t >> 6;            // wave index == head
  const int row0 = blockIdx.x * 64;

#pragma unroll
  for (int i = 0; i < 4; ++i) {
    int q = i * 512 + t;
    int row = q >> 5, c = q & 31;
    int grow = row0 + row; if (grow >= NN) grow = NN - 1;
    const float* src = &h[(size_t)grow * 256 + c * 8];
    float4 f0 = *reinterpret_cast<const float4*>(src);
    float4 f1 = *reinterpret_cast<const float4*>(src + 4);
    uint4 pk;
    pk.x = pack_bf16x2(f0.x, f0.y);
    pk.y = pack_bf16x2(f0.z, f0.w);
    pk.z = pack_bf16x2(f1.x, f1.y);
    pk.w = pack_bf16x2(f1.z, f1.w);
    int sc = c ^ (row & 7);
    *reinterpret_cast<uint4*>(&sA[row * 256 + sc * 8]) = pk;
  }

  bf16x8 bf[2][8];
  {
    const int n = w * 32 + (l & 15);
    const int kb = (l >> 4) * 8;
#pragma unroll
    for (int c = 0; c < 2; ++c)
#pragma unroll
      for (int kk = 0; kk < 8; ++kk)
        bf[c][kk] = *reinterpret_cast<const bf16x8*>(
            &WbT[(size_t)(n + c * 16) * 256 + kk * 32 + kb]);
  }

  f32x4 acc[4][2];
#pragma unroll
  for (int m = 0; m < 4; ++m)
#pragma unroll
    for (int c = 0; c < 2; ++c) acc[m][c] = (f32x4){0.f, 0.f, 0.f, 0.f};

  __syncthreads();

#pragma unroll
  for (int kk = 0; kk < 8; ++kk) {
    bf16x8 af[4];
#pragma unroll
    for (int m = 0; m < 4; ++m) {
      int row = m * 16 + (l & 15);
      int chunk = kk * 4 + (l >> 4);
      int sc = chunk ^ (row & 7);
      af[m] = *reinterpret_cast<const bf16x8*>(&sA[row * 256 + sc * 8]);
    }
#pragma unroll
    for (int m = 0; m < 4; ++m)
#pragma unroll
      for (int c = 0; c < 2; ++c)
        acc[m][c] = __builtin_amdgcn_mfma_f32_16x16x32_bf16(bf[c][kk], af[m], acc[m][c], 0, 0, 0);
  }

  float alc[2][4], arc[2][4];
#pragma unroll
  for (int c = 0; c < 2; ++c)
#pragma unroll
    for (int r = 0; r < 4; ++r) {
      int d = c * 16 + ((l >> 4) << 2) + r;
      alc[c][r] = attn_w[w * 64 + d];
      arc[c][r] = attn_w[w * 64 + 32 + d];
    }

#pragma unroll
  for (int m = 0; m < 4; ++m) {
    int node = row0 + m * 16 + (l & 15);
    float pl = 0.f, pr = 0.f, pm = 0.f;
#pragma unroll
    for (int c = 0; c < 2; ++c)
#pragma unroll
      for (int r = 0; r < 4; ++r) {
        float a = acc[m][c][r];
        pl += a * alc[c][r];
        pr += a * arc[c][r];
        pm = fmaxf(pm, fabsf(a));
      }
    pl += __shfl_xor(pl, 16); pl += __shfl_xor(pl, 32);
    pr += __shfl_xor(pr, 16); pr += __shfl_xor(pr, 32);
    pm = fmaxf(pm, __shfl_xor(pm, 16)); pm = fmaxf(pm, __shfl_xor(pm, 32));
    const float rcp = (pm > 0.f) ? (127.f / pm) : 0.f;

    if (node < NN) {
#pragma unroll
      for (int c = 0; c < 2; ++c) {
        unsigned wq = 0;
#pragma unroll
        for (int r = 0; r < 4; ++r) {
          int q = __float2int_rn(acc[m][c][r] * rcp);
          wq |= ((unsigned)(q & 255)) << (8 * r);
        }
        *reinterpret_cast<unsigned*>(
            &z8[(size_t)node * CC + w * 32 + c * 16 + ((l >> 4) << 2)]) = wq;
      }
      if ((l >> 4) == 0) {
        elsc[(size_t)node * 16 + w] = pl;
        elsc[(size_t)node * 16 + 8 + w] = pm * (1.f / 127.f);
        er[(size_t)node * HH + w] = pr;
      }
    }
  }
}

// ---------- scan: fold 8 rep-counts -> degree scan + per-(node,rep) offsets ----------
__global__ __launch_bounds__(1024) void k_scan(const int* __restrict__ counts8,
                                               int* __restrict__ row_start,
                                               int* __restrict__ partial,
                                               unsigned char* __restrict__ offs8) {
  __shared__ int s[1024];
  const int tid = threadIdx.x;
  const int i = blockIdx.x * 1024 + tid;
  int deg = 0;
  if (i < NN) {
    unsigned pack0 = 0, pack1 = 0;
    int run = 0;
#pragma unroll
    for (int r = 0; r < NREP; ++r) {
      int c = counts8[r * NN + i];
      if (r < 4) pack0 |= (unsigned)run << (8 * r);
      else       pack1 |= (unsigned)run << (8 * (r - 4));
      run += c;
    }
    deg = run;
    uint2 pk; pk.x = pack0; pk.y = pack1;
    *reinterpret_cast<uint2*>(&offs8[(size_t)i * 8]) = pk;
  }
  s[tid] = deg;
  __syncthreads();
  for (int off = 1; off < 1024; off <<= 1) {
    int tv = (tid >= off) ? s[tid - off] : 0;
    __syncthreads();
    s[tid] += tv;
    __syncthreads();
  }
  if (i < NN) row_start[i] = s[tid] - deg;         // exclusive within chunk
  if (tid == 1023) partial[blockIdx.x] = s[1023];  // raw chunk total
}

__device__ __forceinline__ void block_base_scan(const int* __restrict__ partial,
                                                int* __restrict__ sbase) {
  if (threadIdx.x < 64) {
    int l = threadIdx.x;
    int x = (l < NSCAN) ? partial[l] : 0;
    int orig = x;
#pragma unroll
    for (int off = 1; off < 64; off <<= 1) {
      int y = __shfl_up(x, off);
      if (l >= off) x += y;
    }
    sbase[l] = x - orig;
  }
  __syncthreads();
}

// ---------- scatter: atomic-free, contiguous per-node CSR ----------
__global__ __launch_bounds__(256) void k_scatter(const unsigned* __restrict__ sd32,
                                                 const unsigned short* __restrict__ slot16,
                                                 const unsigned char* __restrict__ offs8,
                                                 const int* __restrict__ row_start,
                                                 const int* __restrict__ partial,
                                                 unsigned short* __restrict__ csr16) {
  __shared__ int sbase[64];
  block_base_scan(partial, sbase);
  int stride = gridDim.x * blockDim.x;
  for (int e = blockIdx.x * blockDim.x + threadIdx.x; e < EE; e += stride) {
    unsigned sd = sd32[e];
    int dn = (int)(sd >> 16);
    int rep = ((e & (PREP_STRIDE - 1)) >> 8) & (NREP - 1);
    int pos = row_start[dn] + sbase[dn >> 10] + (int)offs8[dn * 8 + rep] + (int)slot16[e];
    csr16[pos] = (unsigned short)(sd & 0xFFFFu);
  }
}

// ---------- per-node softmax-aggregate (exact R12 known-best body) ----------
#define AGG_WAVES 8192
__global__ __launch_bounds__(256) void k_agg(const signed char* __restrict__ z8,
                                             const float* __restrict__ elsc,
                                             const float* __restrict__ er,
                                             const int* __restrict__ row_start,
                                             const int* __restrict__ partial,
                                             const unsigned short* __restrict__ csr16,
                                             float* __restrict__ out) {
  __shared__ int sbase[64];
  block_base_scan(partial, sbase);

  const int gw = blockIdx.x * 4 + (threadIdx.x >> 6);
  const int l = threadIdx.x & 63;
  const int head = l >> 3;

  for (int n = gw; n < NN; n += AGG_WAVES) {
    const int beg = row_start[n] + sbase[n >> 10];
    const int end = (n == NN - 1) ? EE : (row_start[n + 1] + sbase[(n + 1) >> 10]);
    const float ern = er[(size_t)n * HH + head];

    float den = 0.f;
    float a0 = 0.f, a1 = 0.f, a2 = 0.f, a3 = 0.f;
#pragma unroll 4
    for (int p = beg; p < end; ++p) {
      int s = (int)csr16[p];
      float v = elsc[(size_t)s * 16 + head] + ern;
      v = (v > 0.f) ? v : v * NEG;
      float wgt = __expf(v);
      float sc = elsc[(size_t)s * 16 + 8 + head];
      unsigned wq = *reinterpret_cast<const unsigned*>(&z8[(size_t)s * CC + 4 * l]);
      den += wgt;
      float ws = wgt * sc;
      a0 += ws * (float)(int)(signed char)(wq & 255);
      a1 += ws * (float)(int)(signed char)((wq >> 8) & 255);
      a2 += ws * (float)(int)(signed char)((wq >> 16) & 255);
      a3 += ws * (float)(int)(signed char)(wq >> 24);
    }
    const float rd = (end > beg) ? (1.f / den) : 0.f;
    float4 o;
    o.x = a0 * rd; o.y = a1 * rd; o.z = a2 * rd; o.w = a3 * rd;
    *reinterpret_cast<float4*>(&out[(size_t)n * CC + 4 * l]) = o;
  }
}

extern "C" void kernel_launch(void* const* d_in, const int* in_sizes, int n_in,
                              void* d_out, int out_size, void* d_ws, size_t ws_size,
                              hipStream_t stream) {
  const float* h      = (const float*)d_in[0];
  const float* W      = (const float*)d_in[1];
  const float* attn_w = (const float*)d_in[2];
  const void*  src_raw = d_in[3];
  const void*  dst_raw = d_in[4];
  float* out = (float*)d_out;

  char* ws = (char*)d_ws;
  size_t off = 0;
  signed char* z8     = (signed char*)(ws + off); off += (size_t)NN * CC;            // 12.8 MB
  unsigned short* WbT = (unsigned short*)(ws + off); off += (size_t)INDIM * CC * 2;  // 128 KB
  float* elsc = (float*)(ws + off); off += (size_t)NN * 16 * 4;   // 3.2 MB (el[8]+scale[8])
  float* er   = (float*)(ws + off); off += (size_t)NN * HH * 4;   // 1.6 MB
  int* counts8 = (int*)(ws + off); off += (size_t)NREP * NN * 4;  // 1.6 MB (memset)
  int* row_start = (int*)(ws + off); off += (size_t)NN * 4;
  int* partial   = (int*)(ws + off); off += 256;
  unsigned char* offs8 = (unsigned char*)(ws + off); off += (size_t)NN * 8;    // 400 KB
  unsigned* sd32         = (unsigned*)(ws + off); off += (size_t)EE * 4;       // 3.2 MB
  unsigned short* slot16 = (unsigned short*)(ws + off); off += (size_t)EE * 2; // 1.6 MB
  unsigned short* csr16  = (unsigned short*)(ws + off); off += (size_t)EE * 2; // 1.6 MB

  hipMemsetAsync(counts8, 0, (size_t)NREP * NN * 4, stream);

  k_prep<<<PREP_GRID, 256, 0, stream>>>((const unsigned*)src_raw, (const unsigned*)dst_raw,
                                        counts8, sd32, slot16, W, WbT);

  k_gemm<<<(NN + 63) / 64, 512, 0, stream>>>(h, WbT, attn_w, z8, elsc, er);

  k_scan<<<NSCAN, 1024, 0, stream>>>(counts8, row_start, partial, offs8);

  k_scatter<<<2048, 256, 0, stream>>>(sd32, slot16, offs8, row_start, partial, csr16);

  k_agg<<<AGG_WAVES / 4, 256, 0, stream>>>(z8, elsc, er, row_start, partial, csr16, out);
}

// Round 16
// 142.481 us; speedup vs baseline: 1.0704x; 1.0118x over previous
//
#include <hip/hip_runtime.h>
#include <hip/hip_bf16.h>
#include <math.h>

#define NN 50000
#define EE 800000
#define INDIM 256
#define DD 32
#define HH 8
#define CC 256   // H*D
#define NEG 0.01f
#define NREP 8        // counter replicas == XCD count (rep-major => XCD-local lines)
#define NSCAN 49      // ceil(NN/1024)
#define PREP_GRID 2048
#define PREP_STRIDE (PREP_GRID * 256)   // power of 2 (scatter's rep-recompute relies on this)
#define GEMM_BLOCKS 782  // (NN+63)/64

typedef __attribute__((ext_vector_type(8))) short bf16x8;
typedef __attribute__((ext_vector_type(4))) float f32x4;

__device__ __forceinline__ unsigned short f32_to_bf16_rne(float f) {
  unsigned u = __float_as_uint(f);
  u += 0x7fffu + ((u >> 16) & 1u);
  return (unsigned short)(u >> 16);
}
__device__ __forceinline__ unsigned pack_bf16x2(float a, float b) {
  __hip_bfloat162 p = __float22bfloat162_rn(make_float2(a, b));  // v_cvt_pk_bf16_f32 (RNE)
  return *reinterpret_cast<unsigned*>(&p);
}

// ---------- prep: detect + convert(->packed u32) + XCD-local histogram + W->bf16 ----------
__global__ __launch_bounds__(256) void k_prep(const unsigned* __restrict__ sraw,
                                              const unsigned* __restrict__ draw,
                                              int* __restrict__ counts8,
                                              unsigned* __restrict__ sd32,
                                              unsigned short* __restrict__ slot16,
                                              const float* __restrict__ W,
                                              unsigned short* __restrict__ WbT) {
  __shared__ int sflag;
  if (threadIdx.x == 0) sflag = 0;
  __syncthreads();
  const int gt = blockIdx.x * 256 + threadIdx.x;
  unsigned v = 0;
#pragma unroll
  for (int i = 0; i < 2; ++i) {
    int e = (gt * 2 + i) % (EE / 2);
    v |= sraw[2 * e + 1] | draw[2 * e + 1];
  }
  if (v) atomicOr(&sflag, 1);
  __syncthreads();
  const int is32 = sflag;   // 1 => int32 indices

  const int rep = blockIdx.x & (NREP - 1);
  int* __restrict__ mycounts = counts8 + rep * NN;

  for (int e = gt; e < EE; e += PREP_STRIDE) {
    int sv, dv;
    if (is32) {
      sv = ((const int*)sraw)[e];
      dv = ((const int*)draw)[e];
    } else {
      sv = (int)((const long long*)sraw)[e];
      dv = (int)((const long long*)draw)[e];
    }
    sd32[e] = ((unsigned)dv << 16) | (unsigned)sv;
    slot16[e] = (unsigned short)atomicAdd(&mycounts[dv], 1);
  }

  // W -> WbT[n][k] = W[h][k][d], n=h*32+d (B^T layout)
  if (gt < INDIM * CC) {
    int n = gt >> 8, k = gt & 255;
    int hh = n >> 5, d = n & 31;
    WbT[gt] = f32_to_bf16_rne(W[(size_t)hh * 8192 + k * 32 + d]);
  }
}

// ---------- gemm (+fused scan blocks): z=h@W bf16 MFMA; el/er + int8-quant z epilogue ----------
// Blocks [0, GEMM_BLOCKS): GEMM tile. Blocks [GEMM_BLOCKS, GEMM_BLOCKS+NSCAN):
// 512-thread chunk-scan of counts8 (depends only on k_prep, complete before launch).
__global__ __launch_bounds__(512) void k_gemm(const float* __restrict__ h,
                                              const unsigned short* __restrict__ WbT,
                                              const float* __restrict__ attn_w,
                                              signed char* __restrict__ z8,
                                              float* __restrict__ elsc,
                                              float* __restrict__ er,
                                              const int* __restrict__ counts8,
                                              int* __restrict__ row_start,
                                              int* __restrict__ partial,
                                              unsigned char* __restrict__ offs8) {
  __shared__ short sA[64 * 256];   // 32 KB (gemm tile; scan blocks reuse as int[512])

  if (blockIdx.x >= GEMM_BLOCKS) {
    // ================= SCAN (one block per 1024-node chunk; thread t owns 2 nodes) =====
    int* si = (int*)sA;
    const int cb = blockIdx.x - GEMM_BLOCKS;
    const int tid = threadIdx.x;
    const int i0 = cb * 1024 + tid * 2;
    int d0 = 0, d1 = 0;
#pragma unroll
    for (int which = 0; which < 2; ++which) {
      int i = i0 + which;
      if (i < NN) {
        unsigned pack0 = 0, pack1 = 0;
        int run = 0;
#pragma unroll
        for (int r = 0; r < NREP; ++r) {
          int c = counts8[r * NN + i];
          if (r < 4) pack0 |= (unsigned)run << (8 * r);
          else       pack1 |= (unsigned)run << (8 * (r - 4));
          run += c;
        }
        if (which == 0) d0 = run; else d1 = run;
        uint2 pk; pk.x = pack0; pk.y = pack1;
        *reinterpret_cast<uint2*>(&offs8[(size_t)i * 8]) = pk;
      }
    }
    int pair = d0 + d1;
    si[tid] = pair;
    __syncthreads();
    for (int off = 1; off < 512; off <<= 1) {
      int tv = (tid >= off) ? si[tid - off] : 0;
      __syncthreads();
      si[tid] += tv;
      __syncthreads();
    }
    int ex = si[tid] - pair;   // exclusive prefix within chunk
    if (i0 < NN) row_start[i0] = ex;
    if (i0 + 1 < NN) row_start[i0 + 1] = ex + d0;
    if (tid == 511) partial[cb] = si[511];
    return;
  }

  // ================= GEMM =================
  const int t = threadIdx.x;
  const int l = t & 63;
  const int w = t >> 6;            // wave index == head
  const int row0 = blockIdx.x * 64;

#pragma unroll
  for (int i = 0; i < 4; ++i) {
    int q = i * 512 + t;
    int row = q >> 5, c = q & 31;
    int grow = row0 + row; if (grow >= NN) grow = NN - 1;
    const float* src = &h[(size_t)grow * 256 + c * 8];
    float4 f0 = *reinterpret_cast<const float4*>(src);
    float4 f1 = *reinterpret_cast<const float4*>(src + 4);
    uint4 pk;
    pk.x = pack_bf16x2(f0.x, f0.y);
    pk.y = pack_bf16x2(f0.z, f0.w);
    pk.z = pack_bf16x2(f1.x, f1.y);
    pk.w = pack_bf16x2(f1.z, f1.w);
    int sc = c ^ (row & 7);
    *reinterpret_cast<uint4*>(&sA[row * 256 + sc * 8]) = pk;
  }

  bf16x8 bf[2][8];
  {
    const int n = w * 32 + (l & 15);
    const int kb = (l >> 4) * 8;
#pragma unroll
    for (int c = 0; c < 2; ++c)
#pragma unroll
      for (int kk = 0; kk < 8; ++kk)
        bf[c][kk] = *reinterpret_cast<const bf16x8*>(
            &WbT[(size_t)(n + c * 16) * 256 + kk * 32 + kb]);
  }

  f32x4 acc[4][2];
#pragma unroll
  for (int m = 0; m < 4; ++m)
#pragma unroll
    for (int c = 0; c < 2; ++c) acc[m][c] = (f32x4){0.f, 0.f, 0.f, 0.f};

  __syncthreads();

#pragma unroll
  for (int kk = 0; kk < 8; ++kk) {
    bf16x8 af[4];
#pragma unroll
    for (int m = 0; m < 4; ++m) {
      int row = m * 16 + (l & 15);
      int chunk = kk * 4 + (l >> 4);
      int sc = chunk ^ (row & 7);
      af[m] = *reinterpret_cast<const bf16x8*>(&sA[row * 256 + sc * 8]);
    }
#pragma unroll
    for (int m = 0; m < 4; ++m)
#pragma unroll
      for (int c = 0; c < 2; ++c)
        acc[m][c] = __builtin_amdgcn_mfma_f32_16x16x32_bf16(bf[c][kk], af[m], acc[m][c], 0, 0, 0);
  }

  float alc[2][4], arc[2][4];
#pragma unroll
  for (int c = 0; c < 2; ++c)
#pragma unroll
    for (int r = 0; r < 4; ++r) {
      int d = c * 16 + ((l >> 4) << 2) + r;
      alc[c][r] = attn_w[w * 64 + d];
      arc[c][r] = attn_w[w * 64 + 32 + d];
    }

#pragma unroll
  for (int m = 0; m < 4; ++m) {
    int node = row0 + m * 16 + (l & 15);
    float pl = 0.f, pr = 0.f, pm = 0.f;
#pragma unroll
    for (int c = 0; c < 2; ++c)
#pragma unroll
      for (int r = 0; r < 4; ++r) {
        float a = acc[m][c][r];
        pl += a * alc[c][r];
        pr += a * arc[c][r];
        pm = fmaxf(pm, fabsf(a));
      }
    pl += __shfl_xor(pl, 16); pl += __shfl_xor(pl, 32);
    pr += __shfl_xor(pr, 16); pr += __shfl_xor(pr, 32);
    pm = fmaxf(pm, __shfl_xor(pm, 16)); pm = fmaxf(pm, __shfl_xor(pm, 32));
    const float rcp = (pm > 0.f) ? (127.f / pm) : 0.f;

    if (node < NN) {
#pragma unroll
      for (int c = 0; c < 2; ++c) {
        unsigned wq = 0;
#pragma unroll
        for (int r = 0; r < 4; ++r) {
          int q = __float2int_rn(acc[m][c][r] * rcp);
          wq |= ((unsigned)(q & 255)) << (8 * r);
        }
        *reinterpret_cast<unsigned*>(
            &z8[(size_t)node * CC + w * 32 + c * 16 + ((l >> 4) << 2)]) = wq;
      }
      if ((l >> 4) == 0) {
        elsc[(size_t)node * 16 + w] = pl;
        elsc[(size_t)node * 16 + 8 + w] = pm * (1.f / 127.f);
        er[(size_t)node * HH + w] = pr;
      }
    }
  }
}

__device__ __forceinline__ void block_base_scan(const int* __restrict__ partial,
                                                int* __restrict__ sbase) {
  if (threadIdx.x < 64) {
    int l = threadIdx.x;
    int x = (l < NSCAN) ? partial[l] : 0;
    int orig = x;
#pragma unroll
    for (int off = 1; off < 64; off <<= 1) {
      int y = __shfl_up(x, off);
      if (l >= off) x += y;
    }
    sbase[l] = x - orig;
  }
  __syncthreads();
}

// ---------- scatter: atomic-free, contiguous per-node CSR ----------
__global__ __launch_bounds__(256) void k_scatter(const unsigned* __restrict__ sd32,
                                                 const unsigned short* __restrict__ slot16,
                                                 const unsigned char* __restrict__ offs8,
                                                 const int* __restrict__ row_start,
                                                 const int* __restrict__ partial,
                                                 unsigned short* __restrict__ csr16) {
  __shared__ int sbase[64];
  block_base_scan(partial, sbase);
  int stride = gridDim.x * blockDim.x;
  for (int e = blockIdx.x * blockDim.x + threadIdx.x; e < EE; e += stride) {
    unsigned sd = sd32[e];
    int dn = (int)(sd >> 16);
    int rep = ((e & (PREP_STRIDE - 1)) >> 8) & (NREP - 1);
    int pos = row_start[dn] + sbase[dn >> 10] + (int)offs8[dn * 8 + rep] + (int)slot16[e];
    csr16[pos] = (unsigned short)(sd & 0xFFFFu);
  }
}

// ---------- per-node softmax-aggregate (R12 known-best body; finer-grain grid) ----------
#define AGG_WAVES 16384
__global__ __launch_bounds__(256) void k_agg(const signed char* __restrict__ z8,
                                             const float* __restrict__ elsc,
                                             const float* __restrict__ er,
                                             const int* __restrict__ row_start,
                                             const int* __restrict__ partial,
                                             const unsigned short* __restrict__ csr16,
                                             float* __restrict__ out) {
  __shared__ int sbase[64];
  block_base_scan(partial, sbase);

  const int gw = blockIdx.x * 4 + (threadIdx.x >> 6);
  const int l = threadIdx.x & 63;
  const int head = l >> 3;

  for (int n = gw; n < NN; n += AGG_WAVES) {
    const int beg = row_start[n] + sbase[n >> 10];
    const int end = (n == NN - 1) ? EE : (row_start[n + 1] + sbase[(n + 1) >> 10]);
    const float ern = er[(size_t)n * HH + head];

    float den = 0.f;
    float a0 = 0.f, a1 = 0.f, a2 = 0.f, a3 = 0.f;
#pragma unroll 4
    for (int p = beg; p < end; ++p) {
      int s = (int)csr16[p];
      float v = elsc[(size_t)s * 16 + head] + ern;
      v = (v > 0.f) ? v : v * NEG;
      float wgt = __expf(v);
      float sc = elsc[(size_t)s * 16 + 8 + head];
      unsigned wq = *reinterpret_cast<const unsigned*>(&z8[(size_t)s * CC + 4 * l]);
      den += wgt;
      float ws = wgt * sc;
      a0 += ws * (float)(int)(signed char)(wq & 255);
      a1 += ws * (float)(int)(signed char)((wq >> 8) & 255);
      a2 += ws * (float)(int)(signed char)((wq >> 16) & 255);
      a3 += ws * (float)(int)(signed char)(wq >> 24);
    }
    const float rd = (end > beg) ? (1.f / den) : 0.f;
    float4 o;
    o.x = a0 * rd; o.y = a1 * rd; o.z = a2 * rd; o.w = a3 * rd;
    *reinterpret_cast<float4*>(&out[(size_t)n * CC + 4 * l]) = o;
  }
}

extern "C" void kernel_launch(void* const* d_in, const int* in_sizes, int n_in,
                              void* d_out, int out_size, void* d_ws, size_t ws_size,
                              hipStream_t stream) {
  const float* h      = (const float*)d_in[0];
  const float* W      = (const float*)d_in[1];
  const float* attn_w = (const float*)d_in[2];
  const void*  src_raw = d_in[3];
  const void*  dst_raw = d_in[4];
  float* out = (float*)d_out;

  char* ws = (char*)d_ws;
  size_t off = 0;
  signed char* z8     = (signed char*)(ws + off); off += (size_t)NN * CC;            // 12.8 MB
  unsigned short* WbT = (unsigned short*)(ws + off); off += (size_t)INDIM * CC * 2;  // 128 KB
  float* elsc = (float*)(ws + off); off += (size_t)NN * 16 * 4;   // 3.2 MB (el[8]+scale[8])
  float* er   = (float*)(ws + off); off += (size_t)NN * HH * 4;   // 1.6 MB
  int* counts8 = (int*)(ws + off); off += (size_t)NREP * NN * 4;  // 1.6 MB (memset)
  int* row_start = (int*)(ws + off); off += (size_t)NN * 4;
  int* partial   = (int*)(ws + off); off += 256;
  unsigned char* offs8 = (unsigned char*)(ws + off); off += (size_t)NN * 8;    // 400 KB
  unsigned* sd32         = (unsigned*)(ws + off); off += (size_t)EE * 4;       // 3.2 MB
  unsigned short* slot16 = (unsigned short*)(ws + off); off += (size_t)EE * 2; // 1.6 MB
  unsigned short* csr16  = (unsigned short*)(ws + off); off += (size_t)EE * 2; // 1.6 MB

  hipMemsetAsync(counts8, 0, (size_t)NREP * NN * 4, stream);

  k_prep<<<PREP_GRID, 256, 0, stream>>>((const unsigned*)src_raw, (const unsigned*)dst_raw,
                                        counts8, sd32, slot16, W, WbT);

  k_gemm<<<GEMM_BLOCKS + NSCAN, 512, 0, stream>>>(h, WbT, attn_w, z8, elsc, er,
                                                  counts8, row_start, partial, offs8);

  k_scatter<<<2048, 256, 0, stream>>>(sd32, slot16, offs8, row_start, partial, csr16);

  k_agg<<<AGG_WAVES / 4, 256, 0, stream>>>(z8, elsc, er, row_start, partial, csr16, out);
}

// Round 17
// 138.979 us; speedup vs baseline: 1.0974x; 1.0252x over previous
//
#include <hip/hip_runtime.h>
#include <hip/hip_bf16.h>
#include <math.h>

#define NN 50000
#define EE 800000
#define INDIM 256
#define DD 32
#define HH 8
#define CC 256   // H*D
#define NEG 0.01f
#define NREP 8        // counter replicas == XCD count (rep-major => XCD-local lines)
#define NSCAN 49      // ceil(NN/1024)
#define PREP_GRID 4096
#define PREP_STRIDE (PREP_GRID * 256)   // power of 2, >= EE (scatter's rep-recompute relies on this)
#define GEMM_BLOCKS 782  // (NN+63)/64

typedef __attribute__((ext_vector_type(8))) short bf16x8;
typedef __attribute__((ext_vector_type(4))) float f32x4;

__device__ __forceinline__ unsigned short f32_to_bf16_rne(float f) {
  unsigned u = __float_as_uint(f);
  u += 0x7fffu + ((u >> 16) & 1u);
  return (unsigned short)(u >> 16);
}
__device__ __forceinline__ unsigned pack_bf16x2(float a, float b) {
  __hip_bfloat162 p = __float22bfloat162_rn(make_float2(a, b));  // v_cvt_pk_bf16_f32 (RNE)
  return *reinterpret_cast<unsigned*>(&p);
}

// ---------- prep: detect + convert(->packed u32) + XCD-local histogram + W->bf16 ----------
__global__ __launch_bounds__(256) void k_prep(const unsigned* __restrict__ sraw,
                                              const unsigned* __restrict__ draw,
                                              int* __restrict__ counts8,
                                              unsigned* __restrict__ sd32,
                                              unsigned short* __restrict__ slot16,
                                              const float* __restrict__ W,
                                              unsigned short* __restrict__ WbT) {
  __shared__ int sflag;
  if (threadIdx.x == 0) sflag = 0;
  __syncthreads();
  const int gt = blockIdx.x * 256 + threadIdx.x;
  unsigned v = 0;
  {
    int e = gt % (EE / 2);
    v |= sraw[2 * e + 1] | draw[2 * e + 1];
  }
  if (v) atomicOr(&sflag, 1);
  __syncthreads();
  const int is32 = sflag;   // 1 => int32 indices

  const int rep = blockIdx.x & (NREP - 1);
  int* __restrict__ mycounts = counts8 + rep * NN;

  for (int e = gt; e < EE; e += PREP_STRIDE) {
    int sv, dv;
    if (is32) {
      sv = ((const int*)sraw)[e];
      dv = ((const int*)draw)[e];
    } else {
      sv = (int)((const long long*)sraw)[e];
      dv = (int)((const long long*)draw)[e];
    }
    sd32[e] = ((unsigned)dv << 16) | (unsigned)sv;
    slot16[e] = (unsigned short)atomicAdd(&mycounts[dv], 1);
  }

  // W -> WbT[n][k] = W[h][k][d], n=h*32+d (B^T layout)
  if (gt < INDIM * CC) {
    int n = gt >> 8, k = gt & 255;
    int hh = n >> 5, d = n & 31;
    WbT[gt] = f32_to_bf16_rne(W[(size_t)hh * 8192 + k * 32 + d]);
  }
}

// ---------- gemm (+fused scan blocks): z=h@W bf16 MFMA; el/er + int8-quant z epilogue ----------
__global__ __launch_bounds__(512) void k_gemm(const float* __restrict__ h,
                                              const unsigned short* __restrict__ WbT,
                                              const float* __restrict__ attn_w,
                                              signed char* __restrict__ z8,
                                              float* __restrict__ elsc,
                                              float* __restrict__ er,
                                              const int* __restrict__ counts8,
                                              int* __restrict__ row_start,
                                              int* __restrict__ partial,
                                              unsigned char* __restrict__ offs8) {
  __shared__ short sA[64 * 256];   // 32 KB (gemm tile; scan blocks reuse as int[512])

  if (blockIdx.x >= GEMM_BLOCKS) {
    // ================= SCAN (one block per 1024-node chunk; thread t owns 2 nodes) =====
    int* si = (int*)sA;
    const int cb = blockIdx.x - GEMM_BLOCKS;
    const int tid = threadIdx.x;
    const int i0 = cb * 1024 + tid * 2;
    int d0 = 0, d1 = 0;
#pragma unroll
    for (int which = 0; which < 2; ++which) {
      int i = i0 + which;
      if (i < NN) {
        unsigned pack0 = 0, pack1 = 0;
        int run = 0;
#pragma unroll
        for (int r = 0; r < NREP; ++r) {
          int c = counts8[r * NN + i];
          if (r < 4) pack0 |= (unsigned)run << (8 * r);
          else       pack1 |= (unsigned)run << (8 * (r - 4));
          run += c;
        }
        if (which == 0) d0 = run; else d1 = run;
        uint2 pk; pk.x = pack0; pk.y = pack1;
        *reinterpret_cast<uint2*>(&offs8[(size_t)i * 8]) = pk;
      }
    }
    int pair = d0 + d1;
    si[tid] = pair;
    __syncthreads();
    for (int off = 1; off < 512; off <<= 1) {
      int tv = (tid >= off) ? si[tid - off] : 0;
      __syncthreads();
      si[tid] += tv;
      __syncthreads();
    }
    int ex = si[tid] - pair;   // exclusive prefix within chunk
    if (i0 < NN) row_start[i0] = ex;
    if (i0 + 1 < NN) row_start[i0 + 1] = ex + d0;
    if (tid == 511) partial[cb] = si[511];
    return;
  }

  // ================= GEMM =================
  const int t = threadIdx.x;
  const int l = t & 63;
  const int w = t >> 6;            // wave index == head
  const int row0 = blockIdx.x * 64;

#pragma unroll
  for (int i = 0; i < 4; ++i) {
    int q = i * 512 + t;
    int row = q >> 5, c = q & 31;
    int grow = row0 + row; if (grow >= NN) grow = NN - 1;
    const float* src = &h[(size_t)grow * 256 + c * 8];
    float4 f0 = *reinterpret_cast<const float4*>(src);
    float4 f1 = *reinterpret_cast<const float4*>(src + 4);
    uint4 pk;
    pk.x = pack_bf16x2(f0.x, f0.y);
    pk.y = pack_bf16x2(f0.z, f0.w);
    pk.z = pack_bf16x2(f1.x, f1.y);
    pk.w = pack_bf16x2(f1.z, f1.w);
    int sc = c ^ (row & 7);
    *reinterpret_cast<uint4*>(&sA[row * 256 + sc * 8]) = pk;
  }

  bf16x8 bf[2][8];
  {
    const int n = w * 32 + (l & 15);
    const int kb = (l >> 4) * 8;
#pragma unroll
    for (int c = 0; c < 2; ++c)
#pragma unroll
      for (int kk = 0; kk < 8; ++kk)
        bf[c][kk] = *reinterpret_cast<const bf16x8*>(
            &WbT[(size_t)(n + c * 16) * 256 + kk * 32 + kb]);
  }

  f32x4 acc[4][2];
#pragma unroll
  for (int m = 0; m < 4; ++m)
#pragma unroll
    for (int c = 0; c < 2; ++c) acc[m][c] = (f32x4){0.f, 0.f, 0.f, 0.f};

  __syncthreads();

#pragma unroll
  for (int kk = 0; kk < 8; ++kk) {
    bf16x8 af[4];
#pragma unroll
    for (int m = 0; m < 4; ++m) {
      int row = m * 16 + (l & 15);
      int chunk = kk * 4 + (l >> 4);
      int sc = chunk ^ (row & 7);
      af[m] = *reinterpret_cast<const bf16x8*>(&sA[row * 256 + sc * 8]);
    }
#pragma unroll
    for (int m = 0; m < 4; ++m)
#pragma unroll
      for (int c = 0; c < 2; ++c)
        acc[m][c] = __builtin_amdgcn_mfma_f32_16x16x32_bf16(bf[c][kk], af[m], acc[m][c], 0, 0, 0);
  }

  float alc[2][4], arc[2][4];
#pragma unroll
  for (int c = 0; c < 2; ++c)
#pragma unroll
    for (int r = 0; r < 4; ++r) {
      int d = c * 16 + ((l >> 4) << 2) + r;
      alc[c][r] = attn_w[w * 64 + d];
      arc[c][r] = attn_w[w * 64 + 32 + d];
    }

#pragma unroll
  for (int m = 0; m < 4; ++m) {
    int node = row0 + m * 16 + (l & 15);
    float pl = 0.f, pr = 0.f, pm = 0.f;
#pragma unroll
    for (int c = 0; c < 2; ++c)
#pragma unroll
      for (int r = 0; r < 4; ++r) {
        float a = acc[m][c][r];
        pl += a * alc[c][r];
        pr += a * arc[c][r];
        pm = fmaxf(pm, fabsf(a));
      }
    pl += __shfl_xor(pl, 16); pl += __shfl_xor(pl, 32);
    pr += __shfl_xor(pr, 16); pr += __shfl_xor(pr, 32);
    pm = fmaxf(pm, __shfl_xor(pm, 16)); pm = fmaxf(pm, __shfl_xor(pm, 32));
    const float rcp = (pm > 0.f) ? (127.f / pm) : 0.f;

    if (node < NN) {
#pragma unroll
      for (int c = 0; c < 2; ++c) {
        unsigned wq = 0;
#pragma unroll
        for (int r = 0; r < 4; ++r) {
          int q = __float2int_rn(acc[m][c][r] * rcp);
          wq |= ((unsigned)(q & 255)) << (8 * r);
        }
        *reinterpret_cast<unsigned*>(
            &z8[(size_t)node * CC + w * 32 + c * 16 + ((l >> 4) << 2)]) = wq;
      }
      if ((l >> 4) == 0) {
        elsc[(size_t)node * 16 + w] = pl;
        elsc[(size_t)node * 16 + 8 + w] = pm * (1.f / 127.f);
        er[(size_t)node * HH + w] = pr;
      }
    }
  }
}

__device__ __forceinline__ void block_base_scan(const int* __restrict__ partial,
                                                int* __restrict__ sbase) {
  if (threadIdx.x < 64) {
    int l = threadIdx.x;
    int x = (l < NSCAN) ? partial[l] : 0;
    int orig = x;
#pragma unroll
    for (int off = 1; off < 64; off <<= 1) {
      int y = __shfl_up(x, off);
      if (l >= off) x += y;
    }
    sbase[l] = x - orig;
  }
  __syncthreads();
}

// ---------- scatter: atomic-free, contiguous per-node CSR ----------
// rep recomputed from e (prep's static e->block map): rep = ((e % PREP_STRIDE) >> 8) & 7
__global__ __launch_bounds__(256) void k_scatter(const unsigned* __restrict__ sd32,
                                                 const unsigned short* __restrict__ slot16,
                                                 const unsigned char* __restrict__ offs8,
                                                 const int* __restrict__ row_start,
                                                 const int* __restrict__ partial,
                                                 unsigned short* __restrict__ csr16) {
  __shared__ int sbase[64];
  block_base_scan(partial, sbase);
  int stride = gridDim.x * blockDim.x;
  for (int e = blockIdx.x * blockDim.x + threadIdx.x; e < EE; e += stride) {
    unsigned sd = sd32[e];
    int dn = (int)(sd >> 16);
    int rep = ((e & (PREP_STRIDE - 1)) >> 8) & (NREP - 1);
    int pos = row_start[dn] + sbase[dn >> 10] + (int)offs8[dn * 8 + rep] + (int)slot16[e];
    csr16[pos] = (unsigned short)(sd & 0xFFFFu);
  }
}

// ---------- per-node softmax-aggregate (R12 known-best body; 8192 waves) ----------
#define AGG_WAVES 8192
__global__ __launch_bounds__(256) void k_agg(const signed char* __restrict__ z8,
                                             const float* __restrict__ elsc,
                                             const float* __restrict__ er,
                                             const int* __restrict__ row_start,
                                             const int* __restrict__ partial,
                                             const unsigned short* __restrict__ csr16,
                                             float* __restrict__ out) {
  __shared__ int sbase[64];
  block_base_scan(partial, sbase);

  const int gw = blockIdx.x * 4 + (threadIdx.x >> 6);
  const int l = threadIdx.x & 63;
  const int head = l >> 3;

  for (int n = gw; n < NN; n += AGG_WAVES) {
    const int beg = row_start[n] + sbase[n >> 10];
    const int end = (n == NN - 1) ? EE : (row_start[n + 1] + sbase[(n + 1) >> 10]);
    const float ern = er[(size_t)n * HH + head];

    float den = 0.f;
    float a0 = 0.f, a1 = 0.f, a2 = 0.f, a3 = 0.f;
#pragma unroll 4
    for (int p = beg; p < end; ++p) {
      int s = (int)csr16[p];
      float v = elsc[(size_t)s * 16 + head] + ern;
      v = (v > 0.f) ? v : v * NEG;
      float wgt = __expf(v);
      float sc = elsc[(size_t)s * 16 + 8 + head];
      unsigned wq = *reinterpret_cast<const unsigned*>(&z8[(size_t)s * CC + 4 * l]);
      den += wgt;
      float ws = wgt * sc;
      a0 += ws * (float)(int)(signed char)(wq & 255);
      a1 += ws * (float)(int)(signed char)((wq >> 8) & 255);
      a2 += ws * (float)(int)(signed char)((wq >> 16) & 255);
      a3 += ws * (float)(int)(signed char)(wq >> 24);
    }
    const float rd = (end > beg) ? (1.f / den) : 0.f;
    float4 o;
    o.x = a0 * rd; o.y = a1 * rd; o.z = a2 * rd; o.w = a3 * rd;
    *reinterpret_cast<float4*>(&out[(size_t)n * CC + 4 * l]) = o;
  }
}

extern "C" void kernel_launch(void* const* d_in, const int* in_sizes, int n_in,
                              void* d_out, int out_size, void* d_ws, size_t ws_size,
                              hipStream_t stream) {
  const float* h      = (const float*)d_in[0];
  const float* W      = (const float*)d_in[1];
  const float* attn_w = (const float*)d_in[2];
  const void*  src_raw = d_in[3];
  const void*  dst_raw = d_in[4];
  float* out = (float*)d_out;

  char* ws = (char*)d_ws;
  size_t off = 0;
  signed char* z8     = (signed char*)(ws + off); off += (size_t)NN * CC;            // 12.8 MB
  unsigned short* WbT = (unsigned short*)(ws + off); off += (size_t)INDIM * CC * 2;  // 128 KB
  float* elsc = (float*)(ws + off); off += (size_t)NN * 16 * 4;   // 3.2 MB (el[8]+scale[8])
  float* er   = (float*)(ws + off); off += (size_t)NN * HH * 4;   // 1.6 MB
  int* counts8 = (int*)(ws + off); off += (size_t)NREP * NN * 4;  // 1.6 MB (memset)
  int* row_start = (int*)(ws + off); off += (size_t)NN * 4;
  int* partial   = (int*)(ws + off); off += 256;
  unsigned char* offs8 = (unsigned char*)(ws + off); off += (size_t)NN * 8;    // 400 KB
  unsigned* sd32         = (unsigned*)(ws + off); off += (size_t)EE * 4;       // 3.2 MB
  unsigned short* slot16 = (unsigned short*)(ws + off); off += (size_t)EE * 2; // 1.6 MB
  unsigned short* csr16  = (unsigned short*)(ws + off); off += (size_t)EE * 2; // 1.6 MB

  hipMemsetAsync(counts8, 0, (size_t)NREP * NN * 4, stream);

  k_prep<<<PREP_GRID, 256, 0, stream>>>((const unsigned*)src_raw, (const unsigned*)dst_raw,
                                        counts8, sd32, slot16, W, WbT);

  k_gemm<<<GEMM_BLOCKS + NSCAN, 512, 0, stream>>>(h, WbT, attn_w, z8, elsc, er,
                                                  counts8, row_start, partial, offs8);

  k_scatter<<<4096, 256, 0, stream>>>(sd32, slot16, offs8, row_start, partial, csr16);

  k_agg<<<AGG_WAVES / 4, 256, 0, stream>>>(z8, elsc, er, row_start, partial, csr16, out);
}